// Round 10
// baseline (257.880 us; speedup 1.0000x reference)
//
#include <hip/hip_runtime.h>

#define SEQ 2048
#define DIM 1024

typedef __attribute__((ext_vector_type(8))) __bf16 bf16x8;
typedef __attribute__((ext_vector_type(4))) float f32x4;

typedef __attribute__((address_space(1))) unsigned char gu8_t;
typedef __attribute__((address_space(3))) unsigned char lu8_t;

__device__ __forceinline__ void async_copy16(const void* g, void* l) {
  __builtin_amdgcn_global_load_lds((gu8_t*)g, (lu8_t*)l, 16, 0, 0);
}

__device__ __forceinline__ ushort f2bf(float f) {
  union { float f; unsigned u; } v;
  v.f = f;
  unsigned r = v.u + 0x7FFFu + ((v.u >> 16) & 1u);
  return (ushort)(r >> 16);
}

// Detect input packing (bf16 vs fp32) from x, and zero the lsum accumulator.
__global__ void detect_and_zero(const unsigned* __restrict__ words,
                                int* __restrict__ flag,
                                float* __restrict__ lsum) {
  const int t = threadIdx.x;
  for (int i = t; i < 4 * SEQ; i += 256) lsum[i] = 0.0f;
  if (t < 64) {
    int hits = 0;
    for (int i = 0; i < 64; i++) {
      const unsigned w = words[t * 64 + i];
      const unsigned b = (w >> 8) & 0x7Fu;
      hits += (b >= 0x3Bu && b <= 0x42u) ? 1 : 0;
    }
#pragma unroll
    for (int o = 32; o > 0; o >>= 1) hits += __shfl_xor(hits, o, 64);
    if (t == 0) *flag = (hits > 2048) ? 1 : 0;
  }
}

// Merged prep: blocks [0,4096) convert x -> bf16; blocks [4096,4864)
// transpose the three weight matrices (z = (bid-4096)>>8).
__global__ void prep(const void* __restrict__ xin, const void* __restrict__ w0,
                     const void* __restrict__ w1, const void* __restrict__ w2,
                     ushort* __restrict__ xb, ushort* __restrict__ wt,
                     const int* __restrict__ flag) {
  __shared__ ushort tile[64][68];
  const int bid = blockIdx.x;
  const int t = threadIdx.x;
  const int bf = *flag;

  if (bid < 4096) {
    const int i = bid * 256 + t;
    if (bf) {
      reinterpret_cast<uint4*>(xb)[i] =
          reinterpret_cast<const uint4*>(xin)[i];
    } else {
      const float4* f = reinterpret_cast<const float4*>(xin);
      const float4 a = f[2 * i], b = f[2 * i + 1];
      ushort4 lo, hi;
      lo.x = f2bf(a.x); lo.y = f2bf(a.y); lo.z = f2bf(a.z); lo.w = f2bf(a.w);
      hi.x = f2bf(b.x); hi.y = f2bf(b.y); hi.z = f2bf(b.z); hi.w = f2bf(b.w);
      reinterpret_cast<ushort4*>(xb)[2 * i] = lo;
      reinterpret_cast<ushort4*>(xb)[2 * i + 1] = hi;
    }
    return;
  }

  const int rem = bid - 4096;
  const int z = rem >> 8;
  const int within = rem & 255;
  const int c0 = (within & 15) * 64, r0 = (within >> 4) * 64;
  const void* in = (z == 0) ? w0 : (z == 1) ? w1 : w2;
  ushort* op = wt + (size_t)z * 1024 * 1024;

  if (bf) {
    const ushort* ip = (const ushort*)in;
#pragma unroll
    for (int i = 0; i < 4; i++) {
      const int lin = i * 256 + t;
      const int r = lin >> 4, c4 = (lin & 15) << 2;
      const ushort4 v = *reinterpret_cast<const ushort4*>(
          ip + (size_t)(r0 + r) * 1024 + c0 + c4);
      tile[r][c4 + 0] = v.x; tile[r][c4 + 1] = v.y;
      tile[r][c4 + 2] = v.z; tile[r][c4 + 3] = v.w;
    }
  } else {
    const float* ip = (const float*)in;
#pragma unroll
    for (int i = 0; i < 4; i++) {
      const int lin = i * 256 + t;
      const int r = lin >> 4, c4 = (lin & 15) << 2;
      const float4 v = *reinterpret_cast<const float4*>(
          ip + (size_t)(r0 + r) * 1024 + c0 + c4);
      tile[r][c4 + 0] = f2bf(v.x); tile[r][c4 + 1] = f2bf(v.y);
      tile[r][c4 + 2] = f2bf(v.z); tile[r][c4 + 3] = f2bf(v.w);
    }
  }
  __syncthreads();
#pragma unroll
  for (int i = 0; i < 4; i++) {
    const int lin = i * 256 + t;
    const int c = lin >> 4, r4 = (lin & 15) << 2;
    ushort4 v;
    v.x = tile[r4 + 0][c]; v.y = tile[r4 + 1][c];
    v.z = tile[r4 + 2][c]; v.w = tile[r4 + 3][c];
    *reinterpret_cast<ushort4*>(op + (size_t)(c0 + c) * 1024 + r0 + r4) = v;
  }
}

// Fully-specialized XCD-swizzled TMx128 GEMM: C[M,N] = A[M,K] * Bt[N,:]^T.
// TM in {64,128}. B row stride BRS. SWIZ 0: XCD owns m-stripe (CBAL:
// 8-segment balanced causal pairs). SWIZ 1: XCD owns n-group.
// EPI 0: scale+store | 1: E=exp(S) masked + row-sum atomics | 2: 1/l rows.
// OUTK 0: fp32 | 1: bf16 | 2: by *flag.
template <int EPI, int OUTK, int TRI, int CK, int CBAL, int SWIZ, int TM,
          int M, int N, int K, long AZ, long BZ, long CZ, long BRS>
__global__ __launch_bounds__(256, 4) void gemm_t(
    const ushort* __restrict__ A, const ushort* __restrict__ Bt,
    void* __restrict__ Cv, const int* __restrict__ flag,
    float* __restrict__ lsum, float scale0, float scale1) {
  __shared__ ushort lA[TM * 32];
  __shared__ ushort lB[128 * 32];
  __shared__ float lsh[(EPI == 2) ? TM : 1];

  constexpr int MT = M / TM;
  constexpr int MI = TM / 32;  // m-frags per wave
  const int nT = gridDim.x;
  const int id = blockIdx.y * nT + blockIdx.x;
  const int xcd = id & 7;
  const int loc = id >> 3;
  int nt, mt;
  if constexpr (SWIZ == 1) {
    const int ng = nT >> 3;
    nt = xcd * ng + loc % ng;
    mt = loc / ng;
  } else {
    nt = loc % nT;
    const int s = loc / nT;
    if constexpr (CBAL) {
      const int sh = (s >> 1) << 3;
      mt = ((s & 1) == 0) ? (sh + xcd) : (MT - 1 - sh - xcd);
    } else {
      mt = xcd + (s << 3);
    }
  }
  const int n0 = nt * 128;
  const int m0 = mt * TM;
  if (TRI && n0 > m0 + TM - 1) return;

  const int z = blockIdx.z;
  const ushort* Ab = A + (size_t)z * AZ;
  const ushort* Bb = Bt + (size_t)z * BZ;

  const int t = threadIdx.x;
  const int lane = t & 63;
  const int w = t >> 6;
  const int wm = (w >> 1) * (TM / 2);
  const int wn = (w & 1) * 64;
  const int quad = lane >> 4;
  const int l15 = lane & 15;

  if constexpr (EPI == 2) {
    if (t < TM) lsh[t] = 1.0f / lsum[(size_t)z * M + m0 + t];
  }

  f32x4 acc[MI][4] = {};

  const int kEnd = CK ? ((m0 + TM < K) ? (m0 + TM) : K) : K;

  constexpr int AG = TM * 4;  // 16B-groups in A tile

  for (int k0 = 0; k0 < kEnd; k0 += 32) {
    __syncthreads();
#pragma unroll
    for (int g0 = 0; g0 < AG; g0 += 256) {
      const int g = g0 + t;
      async_copy16(Ab + (size_t)(m0 + (g >> 2)) * K + k0 + ((g & 3) << 3),
                   lA + g * 8);
    }
#pragma unroll
    for (int g0 = 0; g0 < 512; g0 += 256) {
      const int g = g0 + t;
      async_copy16(Bb + (size_t)(n0 + (g >> 2)) * BRS + k0 + ((g & 3) << 3),
                   lB + g * 8);
    }
    __syncthreads();

    bf16x8 af[MI], bfr[4];
#pragma unroll
    for (int mi = 0; mi < MI; mi++)
      af[mi] = *(const bf16x8*)(lA + (wm + mi * 16 + l15) * 32 + quad * 8);
#pragma unroll
    for (int ni = 0; ni < 4; ni++)
      bfr[ni] = *(const bf16x8*)(lB + (wn + ni * 16 + l15) * 32 + quad * 8);
#pragma unroll
    for (int mi = 0; mi < MI; mi++)
#pragma unroll
      for (int ni = 0; ni < 4; ni++)
        acc[mi][ni] = __builtin_amdgcn_mfma_f32_16x16x32_bf16(
            af[mi], bfr[ni], acc[mi][ni], 0, 0, 0);
  }

  const size_t zc = (size_t)z * CZ;

  if constexpr (EPI == 1) {
    ushort* C = (ushort*)Cv + zc;
    float* ls = lsum + (size_t)z * M;
#pragma unroll
    for (int mi = 0; mi < MI; mi++)
#pragma unroll
      for (int r = 0; r < 4; r++) {
        const int row = m0 + wm + mi * 16 + quad * 4 + r;
        float partial = 0.0f;
#pragma unroll
        for (int ni = 0; ni < 4; ni++) {
          const int col = n0 + wn + ni * 16 + l15;
          const float ev = (col <= row) ? __expf(acc[mi][ni][r]) : 0.0f;
          C[(size_t)row * N + col] = f2bf(ev);
          partial += ev;
        }
#pragma unroll
        for (int o = 1; o < 16; o <<= 1) partial += __shfl_xor(partial, o, 64);
        if (l15 == 0) atomicAdd(&ls[row], partial);
      }
    return;
  } else {
    const float scale = (z == 0) ? scale0 : scale1;
    const bool storeBf = (OUTK == 1) || (OUTK == 2 && *flag != 0);
#pragma unroll
    for (int mi = 0; mi < MI; mi++)
#pragma unroll
      for (int ni = 0; ni < 4; ni++)
#pragma unroll
        for (int r = 0; r < 4; r++) {
          const int lrow = wm + mi * 16 + quad * 4 + r;
          const int row = m0 + lrow;
          const int col = n0 + wn + ni * 16 + l15;
          const float sc = (EPI == 2) ? lsh[lrow] : scale;
          const float vv = acc[mi][ni][r] * sc;
          if (storeBf) {
            ushort* C = (ushort*)Cv + zc;
            C[(size_t)row * N + col] = f2bf(vv);
          } else {
            float* C = (float*)Cv + zc;
            C[(size_t)row * N + col] = vv;
          }
        }
  }
}

// Workspace (MB): 0 flag | 1 wt(6) | 7 xb(16) | 23 q(16) | 39 k(16) |
// 55 Vt_all [1024 x 8192] (16) | 71 E bf16(32) | 103 lsum(32KB)
extern "C" void kernel_launch(void* const* d_in, const int* in_sizes, int n_in,
                              void* d_out, int out_size, void* d_ws,
                              size_t ws_size, hipStream_t stream) {
  char* ws = (char*)d_ws;
  const size_t MB = 1024 * 1024;
  int* flag = (int*)ws;
  ushort* wt = (ushort*)(ws + 1 * MB);
  ushort* xb = (ushort*)(ws + 7 * MB);
  ushort* q = (ushort*)(ws + 23 * MB);
  ushort* kk = (ushort*)(ws + 39 * MB);
  ushort* vt = (ushort*)(ws + 55 * MB);
  ushort* sc = (ushort*)(ws + 71 * MB);
  float* lsum = (float*)(ws + 103 * MB);
  (void)kk;

  detect_and_zero<<<dim3(1), 256, 0, stream>>>((const unsigned*)d_in[0], flag,
                                               lsum);

  prep<<<dim3(4864), 256, 0, stream>>>(d_in[0], d_in[1], d_in[2], d_in[3], xb,
                                       wt, flag);

  // Q,K projections: z=0 -> Q (scaled 1/32), z=1 -> K
  gemm_t<0, 1, 0, 0, 0, 0, 128, 8192, 1024, 1024, 0L, 1024L * 1024,
         8192L * 1024, 1024L>
      <<<dim3(8, 64, 2), 256, 0, stream>>>(xb, wt, (void*)q, flag, nullptr,
                                           0.03125f, 1.0f);

  // Vt = Wv^T * X^T: A = wtV [1024x1024], Bt = xb, C = Vt_all [1024x8192]
  gemm_t<0, 1, 0, 0, 0, 1, 128, 1024, 8192, 1024, 0L, 0L, 0L, 1024L>
      <<<dim3(64, 8, 1), 256, 0, stream>>>(wt + 2 * 1024 * 1024, xb,
                                           (void*)vt, flag, nullptr, 1.0f,
                                           1.0f);

  // E = exp(Q*K^T) causal-masked -> bf16, + per-row sums; TM=64 tiles
  gemm_t<1, 1, 1, 0, 1, 0, 64, 2048, 2048, 1024, (long)SEQ * DIM,
         (long)SEQ * DIM, (long)SEQ * SEQ, (long)DIM>
      <<<dim3(16, 32, 4), 256, 0, stream>>>(q, kk, (void*)sc, flag, lsum,
                                            1.0f, 1.0f);

  // out = diag(1/l) * (E @ V^T); TM=64, B = Vt_all slice, row stride 8192
  gemm_t<2, 2, 0, 1, 1, 0, 64, 2048, 1024, 2048, (long)SEQ * SEQ, 2048L,
         (long)SEQ * DIM, 8192L>
      <<<dim3(8, 32, 4), 256, 0, stream>>>(sc, vt, d_out, flag, lsum, 1.0f,
                                           1.0f);
}

// Round 11
// 254.768 us; speedup vs baseline: 1.0122x; 1.0122x over previous
//
#include <hip/hip_runtime.h>

#define SEQ 2048
#define DIM 1024

typedef __attribute__((ext_vector_type(8))) __bf16 bf16x8;
typedef __attribute__((ext_vector_type(4))) float f32x4;

typedef __attribute__((address_space(1))) unsigned char gu8_t;
typedef __attribute__((address_space(3))) unsigned char lu8_t;

__device__ __forceinline__ void async_copy16(const void* g, void* l) {
  __builtin_amdgcn_global_load_lds((gu8_t*)g, (lu8_t*)l, 16, 0, 0);
}

__device__ __forceinline__ ushort f2bf(float f) {
  union { float f; unsigned u; } v;
  v.f = f;
  unsigned r = v.u + 0x7FFFu + ((v.u >> 16) & 1u);
  return (ushort)(r >> 16);
}

// Detect input packing (bf16 vs fp32) from x, and zero the lsum accumulator.
__global__ void detect_and_zero(const unsigned* __restrict__ words,
                                int* __restrict__ flag,
                                float* __restrict__ lsum) {
  const int t = threadIdx.x;
  for (int i = t; i < 4 * SEQ; i += 256) lsum[i] = 0.0f;
  if (t < 64) {
    int hits = 0;
    for (int i = 0; i < 64; i++) {
      const unsigned w = words[t * 64 + i];
      const unsigned b = (w >> 8) & 0x7Fu;
      hits += (b >= 0x3Bu && b <= 0x42u) ? 1 : 0;
    }
#pragma unroll
    for (int o = 32; o > 0; o >>= 1) hits += __shfl_xor(hits, o, 64);
    if (t == 0) *flag = (hits > 2048) ? 1 : 0;
  }
}

// Merged prep: blocks [0,4096) convert x -> bf16; blocks [4096,4864)
// transpose the three weight matrices (z = (bid-4096)>>8).
__global__ void prep(const void* __restrict__ xin, const void* __restrict__ w0,
                     const void* __restrict__ w1, const void* __restrict__ w2,
                     ushort* __restrict__ xb, ushort* __restrict__ wt,
                     const int* __restrict__ flag) {
  __shared__ ushort tile[64][68];
  const int bid = blockIdx.x;
  const int t = threadIdx.x;
  const int bf = *flag;

  if (bid < 4096) {
    const int i = bid * 256 + t;
    if (bf) {
      reinterpret_cast<uint4*>(xb)[i] =
          reinterpret_cast<const uint4*>(xin)[i];
    } else {
      const float4* f = reinterpret_cast<const float4*>(xin);
      const float4 a = f[2 * i], b = f[2 * i + 1];
      ushort4 lo, hi;
      lo.x = f2bf(a.x); lo.y = f2bf(a.y); lo.z = f2bf(a.z); lo.w = f2bf(a.w);
      hi.x = f2bf(b.x); hi.y = f2bf(b.y); hi.z = f2bf(b.z); hi.w = f2bf(b.w);
      reinterpret_cast<ushort4*>(xb)[2 * i] = lo;
      reinterpret_cast<ushort4*>(xb)[2 * i + 1] = hi;
    }
    return;
  }

  const int rem = bid - 4096;
  const int z = rem >> 8;
  const int within = rem & 255;
  const int c0 = (within & 15) * 64, r0 = (within >> 4) * 64;
  const void* in = (z == 0) ? w0 : (z == 1) ? w1 : w2;
  ushort* op = wt + (size_t)z * 1024 * 1024;

  if (bf) {
    const ushort* ip = (const ushort*)in;
#pragma unroll
    for (int i = 0; i < 4; i++) {
      const int lin = i * 256 + t;
      const int r = lin >> 4, c4 = (lin & 15) << 2;
      const ushort4 v = *reinterpret_cast<const ushort4*>(
          ip + (size_t)(r0 + r) * 1024 + c0 + c4);
      tile[r][c4 + 0] = v.x; tile[r][c4 + 1] = v.y;
      tile[r][c4 + 2] = v.z; tile[r][c4 + 3] = v.w;
    }
  } else {
    const float* ip = (const float*)in;
#pragma unroll
    for (int i = 0; i < 4; i++) {
      const int lin = i * 256 + t;
      const int r = lin >> 4, c4 = (lin & 15) << 2;
      const float4 v = *reinterpret_cast<const float4*>(
          ip + (size_t)(r0 + r) * 1024 + c0 + c4);
      tile[r][c4 + 0] = f2bf(v.x); tile[r][c4 + 1] = f2bf(v.y);
      tile[r][c4 + 2] = f2bf(v.z); tile[r][c4 + 3] = f2bf(v.w);
    }
  }
  __syncthreads();
#pragma unroll
  for (int i = 0; i < 4; i++) {
    const int lin = i * 256 + t;
    const int c = lin >> 4, r4 = (lin & 15) << 2;
    ushort4 v;
    v.x = tile[r4 + 0][c]; v.y = tile[r4 + 1][c];
    v.z = tile[r4 + 2][c]; v.w = tile[r4 + 3][c];
    *reinterpret_cast<ushort4*>(op + (size_t)(c0 + c) * 1024 + r0 + r4) = v;
  }
}

// Fully-specialized XCD-swizzled 128x128 GEMM, BK=64 K-steps (half the
// barrier drains of BK=32 — the latency floor for short-K kernels).
// C[M,N] = A[M,K] * Bt[N,:]^T. B row stride BRS.
// SWIZ 0: XCD owns m-stripe (CBAL: balanced causal pairs {x, MT-1-x}).
// SWIZ 1: XCD owns n-group.
// EPI 0: scale+store | 1: E=exp(S) masked + row-sum atomics | 2: 1/l rows.
// OUTK 0: fp32 | 1: bf16 | 2: by *flag.
template <int EPI, int OUTK, int TRI, int CK, int CBAL, int SWIZ, int M,
          int N, int K, long AZ, long BZ, long CZ, long BRS>
__global__ __launch_bounds__(256, 4) void gemm_t(
    const ushort* __restrict__ A, const ushort* __restrict__ Bt,
    void* __restrict__ Cv, const int* __restrict__ flag,
    float* __restrict__ lsum, float scale0, float scale1) {
  __shared__ ushort lA[128 * 64];
  __shared__ ushort lB[128 * 64];
  __shared__ float lsh[(EPI == 2) ? 128 : 1];

  constexpr int MT = M / 128;
  const int nT = gridDim.x;
  const int id = blockIdx.y * nT + blockIdx.x;
  const int xcd = id & 7;
  const int loc = id >> 3;
  int nt, mt;
  if constexpr (SWIZ == 1) {
    const int ng = nT >> 3;
    nt = xcd * ng + loc % ng;
    mt = loc / ng;
  } else {
    nt = loc % nT;
    const int s = loc / nT;
    if constexpr (CBAL) {
      mt = (s == 0) ? xcd : (MT - 1 - xcd);
    } else {
      mt = xcd + (s << 3);
    }
  }
  const int n0 = nt * 128;
  const int m0 = mt * 128;
  if (TRI && n0 > m0 + 127) return;

  const int z = blockIdx.z;
  const ushort* Ab = A + (size_t)z * AZ;
  const ushort* Bb = Bt + (size_t)z * BZ;

  const int t = threadIdx.x;
  const int lane = t & 63;
  const int w = t >> 6;
  const int wm = (w >> 1) * 64;
  const int wn = (w & 1) * 64;
  const int quad = lane >> 4;
  const int l15 = lane & 15;

  if constexpr (EPI == 2) {
    if (t < 128) lsh[t] = 1.0f / lsum[(size_t)z * M + m0 + t];
  }

  f32x4 acc[4][4] = {};

  const int kEnd = CK ? ((m0 + 128 < K) ? (m0 + 128) : K) : K;

  for (int k0 = 0; k0 < kEnd; k0 += 64) {
    __syncthreads();
    // stage A and B 128x64 tiles: 8 x 16B per thread (1024 groups each)
#pragma unroll
    for (int g0 = 0; g0 < 1024; g0 += 256) {
      const int g = g0 + t;
      const int r = g >> 3, c = (g & 7) << 3;
      async_copy16(Ab + (size_t)(m0 + r) * K + k0 + c, lA + g * 8);
    }
#pragma unroll
    for (int g0 = 0; g0 < 1024; g0 += 256) {
      const int g = g0 + t;
      const int r = g >> 3, c = (g & 7) << 3;
      async_copy16(Bb + (size_t)(n0 + r) * BRS + k0 + c, lB + g * 8);
    }
    __syncthreads();

    // two k-halves processed sequentially to keep the live fragment set small
#pragma unroll
    for (int h = 0; h < 2; h++) {
      bf16x8 af[4], bfr[4];
#pragma unroll
      for (int mi = 0; mi < 4; mi++)
        af[mi] = *(const bf16x8*)(lA + (wm + mi * 16 + l15) * 64 + h * 32 +
                                  quad * 8);
#pragma unroll
      for (int ni = 0; ni < 4; ni++)
        bfr[ni] = *(const bf16x8*)(lB + (wn + ni * 16 + l15) * 64 + h * 32 +
                                   quad * 8);
#pragma unroll
      for (int mi = 0; mi < 4; mi++)
#pragma unroll
        for (int ni = 0; ni < 4; ni++)
          acc[mi][ni] = __builtin_amdgcn_mfma_f32_16x16x32_bf16(
              af[mi], bfr[ni], acc[mi][ni], 0, 0, 0);
    }
  }

  const size_t zc = (size_t)z * CZ;

  if constexpr (EPI == 1) {
    ushort* C = (ushort*)Cv + zc;
    float* ls = lsum + (size_t)z * M;
#pragma unroll
    for (int mi = 0; mi < 4; mi++)
#pragma unroll
      for (int r = 0; r < 4; r++) {
        const int row = m0 + wm + mi * 16 + quad * 4 + r;
        float partial = 0.0f;
#pragma unroll
        for (int ni = 0; ni < 4; ni++) {
          const int col = n0 + wn + ni * 16 + l15;
          const float ev = (col <= row) ? __expf(acc[mi][ni][r]) : 0.0f;
          C[(size_t)row * N + col] = f2bf(ev);
          partial += ev;
        }
#pragma unroll
        for (int o = 1; o < 16; o <<= 1) partial += __shfl_xor(partial, o, 64);
        if (l15 == 0) atomicAdd(&ls[row], partial);
      }
    return;
  } else {
    const float scale = (z == 0) ? scale0 : scale1;
    const bool storeBf = (OUTK == 1) || (OUTK == 2 && *flag != 0);
#pragma unroll
    for (int mi = 0; mi < 4; mi++)
#pragma unroll
      for (int ni = 0; ni < 4; ni++)
#pragma unroll
        for (int r = 0; r < 4; r++) {
          const int lrow = wm + mi * 16 + quad * 4 + r;
          const int row = m0 + lrow;
          const int col = n0 + wn + ni * 16 + l15;
          const float sc = (EPI == 2) ? lsh[lrow] : scale;
          const float vv = acc[mi][ni][r] * sc;
          if (storeBf) {
            ushort* C = (ushort*)Cv + zc;
            C[(size_t)row * N + col] = f2bf(vv);
          } else {
            float* C = (float*)Cv + zc;
            C[(size_t)row * N + col] = vv;
          }
        }
  }
}

// Workspace (MB): 0 flag | 1 wt(6) | 7 xb(16) | 23 q(16) | 39 k(16) |
// 55 Vt_all [1024 x 8192] (16) | 71 E bf16(32) | 103 lsum(32KB)
extern "C" void kernel_launch(void* const* d_in, const int* in_sizes, int n_in,
                              void* d_out, int out_size, void* d_ws,
                              size_t ws_size, hipStream_t stream) {
  char* ws = (char*)d_ws;
  const size_t MB = 1024 * 1024;
  int* flag = (int*)ws;
  ushort* wt = (ushort*)(ws + 1 * MB);
  ushort* xb = (ushort*)(ws + 7 * MB);
  ushort* q = (ushort*)(ws + 23 * MB);
  ushort* kk = (ushort*)(ws + 39 * MB);
  ushort* vt = (ushort*)(ws + 55 * MB);
  ushort* sc = (ushort*)(ws + 71 * MB);
  float* lsum = (float*)(ws + 103 * MB);
  (void)kk;

  detect_and_zero<<<dim3(1), 256, 0, stream>>>((const unsigned*)d_in[0], flag,
                                               lsum);

  prep<<<dim3(4864), 256, 0, stream>>>(d_in[0], d_in[1], d_in[2], d_in[3], xb,
                                       wt, flag);

  // Q,K projections: z=0 -> Q (scaled 1/32), z=1 -> K
  gemm_t<0, 1, 0, 0, 0, 0, 8192, 1024, 1024, 0L, 1024L * 1024, 8192L * 1024,
         1024L>
      <<<dim3(8, 64, 2), 256, 0, stream>>>(xb, wt, (void*)q, flag, nullptr,
                                           0.03125f, 1.0f);

  // Vt = Wv^T * X^T: A = wtV [1024x1024], Bt = xb, C = Vt_all [1024x8192]
  gemm_t<0, 1, 0, 0, 0, 1, 1024, 8192, 1024, 0L, 0L, 0L, 1024L>
      <<<dim3(64, 8, 1), 256, 0, stream>>>(wt + 2 * 1024 * 1024, xb,
                                           (void*)vt, flag, nullptr, 1.0f,
                                           1.0f);

  // E = exp(Q*K^T) causal-masked -> bf16, + per-row sums
  gemm_t<1, 1, 1, 0, 1, 0, 2048, 2048, 1024, (long)SEQ * DIM, (long)SEQ * DIM,
         (long)SEQ * SEQ, (long)DIM>
      <<<dim3(16, 16, 4), 256, 0, stream>>>(q, kk, (void*)sc, flag, lsum,
                                            1.0f, 1.0f);

  // out = diag(1/l) * (E @ V^T); B = Vt_all batch slice, row stride 8192
  gemm_t<2, 2, 0, 1, 1, 0, 2048, 1024, 2048, (long)SEQ * SEQ, 2048L,
         (long)SEQ * DIM, 8192L>
      <<<dim3(8, 16, 4), 256, 0, stream>>>(sc, vt, d_out, flag, lsum, 1.0f,
                                           1.0f);
}

// Round 12
// 243.983 us; speedup vs baseline: 1.0570x; 1.0442x over previous
//
#include <hip/hip_runtime.h>

#define SEQ 2048
#define DIM 1024

typedef __attribute__((ext_vector_type(8))) __bf16 bf16x8;
typedef __attribute__((ext_vector_type(4))) float f32x4;

typedef __attribute__((address_space(1))) unsigned char gu8_t;
typedef __attribute__((address_space(3))) unsigned char lu8_t;

__device__ __forceinline__ void async_copy16(const void* g, void* l) {
  __builtin_amdgcn_global_load_lds((gu8_t*)g, (lu8_t*)l, 16, 0, 0);
}

__device__ __forceinline__ ushort f2bf(float f) {
  union { float f; unsigned u; } v;
  v.f = f;
  unsigned r = v.u + 0x7FFFu + ((v.u >> 16) & 1u);
  return (ushort)(r >> 16);
}

// Merged prep:
//   blocks [0,4096):    convert x -> bf16 xb
//   blocks [4096,4864): transpose the three weight matrices
//   blocks [4864,4872): zero lsum (+ block 4864 publishes the dtype flag)
// Every block detects the dtype locally from the same 4 KB sample of x
// (bf16-packed: ~99% byte-1 hits; fp32: ~6% — threshold 50% is exact).
__global__ void prep(const void* __restrict__ xin, const void* __restrict__ w0,
                     const void* __restrict__ w1, const void* __restrict__ w2,
                     ushort* __restrict__ xb, ushort* __restrict__ wt,
                     int* __restrict__ flag, float* __restrict__ lsum) {
  __shared__ ushort tile[64][68];
  __shared__ int redi[4];
  const int bid = blockIdx.x;
  const int t = threadIdx.x;

  // local dtype detection (uniform across blocks)
  const unsigned* words = (const unsigned*)xin;
  int hits = 0;
#pragma unroll
  for (int i = 0; i < 4; i++) {
    const unsigned wv = words[t * 4 + i];
    const unsigned b = (wv >> 8) & 0x7Fu;
    hits += (b >= 0x3Bu && b <= 0x42u) ? 1 : 0;
  }
#pragma unroll
  for (int o = 32; o > 0; o >>= 1) hits += __shfl_xor(hits, o, 64);
  if ((t & 63) == 0) redi[t >> 6] = hits;
  __syncthreads();
  const int bf = (redi[0] + redi[1] + redi[2] + redi[3] > 512) ? 1 : 0;

  if (bid >= 4864) {
    reinterpret_cast<float4*>(lsum)[(bid - 4864) * 256 + t] =
        make_float4(0.f, 0.f, 0.f, 0.f);
    if (bid == 4864 && t == 0) *flag = bf;
    return;
  }

  if (bid < 4096) {
    const int i = bid * 256 + t;
    if (bf) {
      reinterpret_cast<uint4*>(xb)[i] =
          reinterpret_cast<const uint4*>(xin)[i];
    } else {
      const float4* f = reinterpret_cast<const float4*>(xin);
      const float4 a = f[2 * i], b = f[2 * i + 1];
      ushort4 lo, hi;
      lo.x = f2bf(a.x); lo.y = f2bf(a.y); lo.z = f2bf(a.z); lo.w = f2bf(a.w);
      hi.x = f2bf(b.x); hi.y = f2bf(b.y); hi.z = f2bf(b.z); hi.w = f2bf(b.w);
      reinterpret_cast<ushort4*>(xb)[2 * i] = lo;
      reinterpret_cast<ushort4*>(xb)[2 * i + 1] = hi;
    }
    return;
  }

  const int rem = bid - 4096;
  const int z = rem >> 8;
  const int within = rem & 255;
  const int c0 = (within & 15) * 64, r0 = (within >> 4) * 64;
  const void* in = (z == 0) ? w0 : (z == 1) ? w1 : w2;
  ushort* op = wt + (size_t)z * 1024 * 1024;

  if (bf) {
    const ushort* ip = (const ushort*)in;
#pragma unroll
    for (int i = 0; i < 4; i++) {
      const int lin = i * 256 + t;
      const int r = lin >> 4, c4 = (lin & 15) << 2;
      const ushort4 v = *reinterpret_cast<const ushort4*>(
          ip + (size_t)(r0 + r) * 1024 + c0 + c4);
      tile[r][c4 + 0] = v.x; tile[r][c4 + 1] = v.y;
      tile[r][c4 + 2] = v.z; tile[r][c4 + 3] = v.w;
    }
  } else {
    const float* ip = (const float*)in;
#pragma unroll
    for (int i = 0; i < 4; i++) {
      const int lin = i * 256 + t;
      const int r = lin >> 4, c4 = (lin & 15) << 2;
      const float4 v = *reinterpret_cast<const float4*>(
          ip + (size_t)(r0 + r) * 1024 + c0 + c4);
      tile[r][c4 + 0] = f2bf(v.x); tile[r][c4 + 1] = f2bf(v.y);
      tile[r][c4 + 2] = f2bf(v.z); tile[r][c4 + 3] = f2bf(v.w);
    }
  }
  __syncthreads();
#pragma unroll
  for (int i = 0; i < 4; i++) {
    const int lin = i * 256 + t;
    const int c = lin >> 4, r4 = (lin & 15) << 2;
    ushort4 v;
    v.x = tile[r4 + 0][c]; v.y = tile[r4 + 1][c];
    v.z = tile[r4 + 2][c]; v.w = tile[r4 + 3][c];
    *reinterpret_cast<ushort4*>(op + (size_t)(c0 + c) * 1024 + r0 + r4) = v;
  }
}

// Fully-specialized XCD-swizzled 128x128 GEMM, BK=64.
// C[M,N] = A[M,K] * Bt[N,:]^T, B row stride BRS.
// SWIZ 0: m-striped (proj)            grid (nT, MT/8, z)
// SWIZ 1: n-grouped per XCD (vtproj)  grid (nT, MT, 1), nT%8==0
// SWIZ 2: exact balanced causal tri   grid (8, 17, z), MT==16: XCD r owns
//         m-tiles {r, 15-r}; loc<=r -> (r, loc) else (15-r, loc-r-1)
// SWIZ 3: n-tile == XCD (PV)          grid (8, MT, z)
// EPI 0: scale+store | 1: E=exp(S) masked + row-sum atomics | 2: 1/l rows.
// OUTK 0: fp32 | 1: bf16 | 2: by *flag. CK: kEnd = min(m0+128, K).
template <int EPI, int OUTK, int CK, int SWIZ, int M, int N, int K, long AZ,
          long BZ, long CZ, long BRS>
__global__ __launch_bounds__(256, 4) void gemm_t(
    const ushort* __restrict__ A, const ushort* __restrict__ Bt,
    void* __restrict__ Cv, const int* __restrict__ flag,
    float* __restrict__ lsum, float scale0, float scale1) {
  __shared__ ushort lA[128 * 64];
  __shared__ ushort lB[128 * 64];
  __shared__ float lsh[(EPI == 2) ? 128 : 1];

  constexpr int MT = M / 128;
  const int nT = gridDim.x;
  const int id = blockIdx.y * nT + blockIdx.x;
  const int xcd = id & 7;
  const int loc = id >> 3;
  int nt, mt;
  if constexpr (SWIZ == 1) {
    const int ng = nT >> 3;
    nt = xcd * ng + loc % ng;
    mt = loc / ng;
  } else if constexpr (SWIZ == 2) {
    if (loc <= xcd) { mt = xcd; nt = loc; }
    else { mt = MT - 1 - xcd; nt = loc - xcd - 1; }
  } else if constexpr (SWIZ == 3) {
    nt = xcd;
    mt = loc;
  } else {
    nt = loc % nT;
    mt = xcd + ((loc / nT) << 3);
  }
  const int n0 = nt * 128;
  const int m0 = mt * 128;

  const int z = blockIdx.z;
  const ushort* Ab = A + (size_t)z * AZ;
  const ushort* Bb = Bt + (size_t)z * BZ;

  const int t = threadIdx.x;
  const int lane = t & 63;
  const int w = t >> 6;
  const int wm = (w >> 1) * 64;
  const int wn = (w & 1) * 64;
  const int quad = lane >> 4;
  const int l15 = lane & 15;

  if constexpr (EPI == 2) {
    if (t < 128) lsh[t] = 1.0f / lsum[(size_t)z * M + m0 + t];
  }

  f32x4 acc[4][4] = {};

  const int kEnd = CK ? ((m0 + 128 < K) ? (m0 + 128) : K) : K;

  for (int k0 = 0; k0 < kEnd; k0 += 64) {
    __syncthreads();
#pragma unroll
    for (int g0 = 0; g0 < 1024; g0 += 256) {
      const int g = g0 + t;
      const int r = g >> 3, c = (g & 7) << 3;
      async_copy16(Ab + (size_t)(m0 + r) * K + k0 + c, lA + g * 8);
    }
#pragma unroll
    for (int g0 = 0; g0 < 1024; g0 += 256) {
      const int g = g0 + t;
      const int r = g >> 3, c = (g & 7) << 3;
      async_copy16(Bb + (size_t)(n0 + r) * BRS + k0 + c, lB + g * 8);
    }
    __syncthreads();

#pragma unroll
    for (int h = 0; h < 2; h++) {
      bf16x8 af[4], bfr[4];
#pragma unroll
      for (int mi = 0; mi < 4; mi++)
        af[mi] = *(const bf16x8*)(lA + (wm + mi * 16 + l15) * 64 + h * 32 +
                                  quad * 8);
#pragma unroll
      for (int ni = 0; ni < 4; ni++)
        bfr[ni] = *(const bf16x8*)(lB + (wn + ni * 16 + l15) * 64 + h * 32 +
                                   quad * 8);
#pragma unroll
      for (int mi = 0; mi < 4; mi++)
#pragma unroll
        for (int ni = 0; ni < 4; ni++)
          acc[mi][ni] = __builtin_amdgcn_mfma_f32_16x16x32_bf16(
              af[mi], bfr[ni], acc[mi][ni], 0, 0, 0);
    }
  }

  const size_t zc = (size_t)z * CZ;

  if constexpr (EPI == 1) {
    ushort* C = (ushort*)Cv + zc;
    float* ls = lsum + (size_t)z * M;
#pragma unroll
    for (int mi = 0; mi < 4; mi++)
#pragma unroll
      for (int r = 0; r < 4; r++) {
        const int row = m0 + wm + mi * 16 + quad * 4 + r;
        float partial = 0.0f;
#pragma unroll
        for (int ni = 0; ni < 4; ni++) {
          const int col = n0 + wn + ni * 16 + l15;
          const float ev = (col <= row) ? __expf(acc[mi][ni][r]) : 0.0f;
          C[(size_t)row * N + col] = f2bf(ev);
          partial += ev;
        }
#pragma unroll
        for (int o = 1; o < 16; o <<= 1) partial += __shfl_xor(partial, o, 64);
        if (l15 == 0) atomicAdd(&ls[row], partial);
      }
    return;
  } else {
    const float scale = (z == 0) ? scale0 : scale1;
    const bool storeBf = (OUTK == 1) || (OUTK == 2 && *flag != 0);
#pragma unroll
    for (int mi = 0; mi < 4; mi++)
#pragma unroll
      for (int ni = 0; ni < 4; ni++)
#pragma unroll
        for (int r = 0; r < 4; r++) {
          const int lrow = wm + mi * 16 + quad * 4 + r;
          const int row = m0 + lrow;
          const int col = n0 + wn + ni * 16 + l15;
          const float sc = (EPI == 2) ? lsh[lrow] : scale;
          const float vv = acc[mi][ni][r] * sc;
          if (storeBf) {
            ushort* C = (ushort*)Cv + zc;
            C[(size_t)row * N + col] = f2bf(vv);
          } else {
            float* C = (float*)Cv + zc;
            C[(size_t)row * N + col] = vv;
          }
        }
  }
}

// Workspace (MB): 0 flag | 1 wt(6) | 7 xb(16) | 23 q(16) | 39 k(16) |
// 55 Vt_all [1024 x 8192] (16) | 71 E bf16(32) | 103 lsum(32KB)
extern "C" void kernel_launch(void* const* d_in, const int* in_sizes, int n_in,
                              void* d_out, int out_size, void* d_ws,
                              size_t ws_size, hipStream_t stream) {
  char* ws = (char*)d_ws;
  const size_t MB = 1024 * 1024;
  int* flag = (int*)ws;
  ushort* wt = (ushort*)(ws + 1 * MB);
  ushort* xb = (ushort*)(ws + 7 * MB);
  ushort* q = (ushort*)(ws + 23 * MB);
  ushort* kk = (ushort*)(ws + 39 * MB);
  ushort* vt = (ushort*)(ws + 55 * MB);
  ushort* sc = (ushort*)(ws + 71 * MB);
  float* lsum = (float*)(ws + 103 * MB);
  (void)kk;

  prep<<<dim3(4872), 256, 0, stream>>>(d_in[0], d_in[1], d_in[2], d_in[3], xb,
                                       wt, flag, lsum);

  // Q,K projections: z=0 -> Q (scaled 1/32), z=1 -> K
  gemm_t<0, 1, 0, 0, 8192, 1024, 1024, 0L, 1024L * 1024, 8192L * 1024, 1024L>
      <<<dim3(8, 64, 2), 256, 0, stream>>>(xb, wt, (void*)q, flag, nullptr,
                                           0.03125f, 1.0f);

  // Vt = Wv^T * X^T: A = wtV [1024x1024], Bt = xb, C = Vt_all [1024x8192]
  gemm_t<0, 1, 0, 1, 1024, 8192, 1024, 0L, 0L, 0L, 1024L>
      <<<dim3(64, 8, 1), 256, 0, stream>>>(wt + 2 * 1024 * 1024, xb,
                                           (void*)vt, flag, nullptr, 1.0f,
                                           1.0f);

  // E = exp(Q*K^T) causal-masked -> bf16, + per-row sums; exact tri grid
  gemm_t<1, 1, 0, 2, 2048, 2048, 1024, (long)SEQ * DIM, (long)SEQ * DIM,
         (long)SEQ * SEQ, (long)DIM>
      <<<dim3(8, 17, 4), 256, 0, stream>>>(q, kk, (void*)sc, flag, lsum, 1.0f,
                                           1.0f);

  // out = diag(1/l) * (E @ V^T); XCD owns n-tile (Vt slab L2-resident)
  gemm_t<2, 2, 1, 3, 2048, 1024, 2048, (long)SEQ * SEQ, 2048L,
         (long)SEQ * DIM, 8192L>
      <<<dim3(8, 16, 4), 256, 0, stream>>>(sc, vt, d_out, flag, lsum, 1.0f,
                                           1.0f);
}